// Round 1
// baseline (127.226 us; speedup 1.0000x reference)
//
#include <hip/hip_runtime.h>

#define B_IMG 16
#define A_N   65536
#define M_N   64

// Kernel 1: per-(image, anchor) IoU argmax + smooth-L1, reduced to per-image
// (loss_sum, pos_count) accumulators in workspace.
__global__ __launch_bounds__(256) void rl_main(
    const float* __restrict__ reg,      // (B, A, 2)
    const float* __restrict__ anchors,  // (1, A, 2)
    const float* __restrict__ ann,      // (B, M, 3)
    float* __restrict__ ws_sum,         // [B]
    float* __restrict__ ws_cnt)         // [B]
{
    __shared__ float sb0[M_N], sb1[M_N], sarea[M_N], svalid[M_N];
    const int b   = blockIdx.y;
    const int tid = threadIdx.x;

    if (tid < M_N) {
        const float* p = ann + (b * M_N + tid) * 3;
        float b0 = p[0], b1 = p[1], v = p[2];
        sb0[tid]    = b0;
        sb1[tid]    = b1;
        sarea[tid]  = b1 - b0;
        svalid[tid] = (v != -1.0f) ? 1.0f : 0.0f;
    }
    __syncthreads();

    const int a = blockIdx.x * blockDim.x + tid;
    const float2 an = ((const float2*)anchors)[a];
    const float aw   = an.y - an.x;
    const float actr = an.x + 0.5f * aw;

    // argmax over M (first-occurrence on ties: strict > update)
    float best  = -2.0f;
    int   besti = 0;
    #pragma unroll 8
    for (int m = 0; m < M_N; ++m) {
        float iw = fminf(an.y, sb1[m]) - fmaxf(an.x, sb0[m]);
        iw = fmaxf(iw, 0.0f);
        float ua  = fmaxf(aw + sarea[m] - iw, 1e-8f);
        float iou = iw / ua;
        iou = (svalid[m] != 0.0f) ? iou : -1.0f;
        if (iou > best) { best = iou; besti = m; }
    }

    float lsum = 0.0f, lcnt = 0.0f;
    if (best >= 0.5f) {
        lcnt = 1.0f;
        float g0   = sb0[besti];
        float g1   = sb1[besti];
        float gw   = g1 - g0;
        float gctr = g0 + 0.5f * gw;
        gw = fmaxf(gw, 1.0f);
        float tdx = (gctr - actr) / aw / 0.1f;
        float tdw = logf(gw / aw) / 0.2f;
        const float2 r = ((const float2*)reg)[(size_t)b * A_N + a];
        float d0 = fabsf(tdx - r.x);
        float d1 = fabsf(tdw - r.y);
        const float third = 1.0f / 9.0f;
        lsum  = (d0 <= third) ? 4.5f * d0 * d0 : d0 - (0.5f / 9.0f);
        lsum += (d1 <= third) ? 4.5f * d1 * d1 : d1 - (0.5f / 9.0f);
    }

    // wave (64-lane) shuffle reduction
    #pragma unroll
    for (int off = 32; off > 0; off >>= 1) {
        lsum += __shfl_down(lsum, off, 64);
        lcnt += __shfl_down(lcnt, off, 64);
    }
    __shared__ float rs[4], rc[4];
    const int wave = tid >> 6;
    const int lane = tid & 63;
    if (lane == 0) { rs[wave] = lsum; rc[wave] = lcnt; }
    __syncthreads();
    if (tid == 0) {
        float s = rs[0] + rs[1] + rs[2] + rs[3];
        float c = rc[0] + rc[1] + rc[2] + rc[3];
        atomicAdd(&ws_sum[b], s);
        atomicAdd(&ws_cnt[b], c);
    }
}

// Kernel 2: per-image normalization + mean over B. One wave.
__global__ void rl_final(const float* __restrict__ ws_sum,
                         const float* __restrict__ ws_cnt,
                         float* __restrict__ out)
{
    const int tid = threadIdx.x;
    float loss = 0.0f;
    if (tid < B_IMG) {
        float c = ws_cnt[tid];
        float s = ws_sum[tid];
        float denom = 2.0f * fmaxf(c, 1.0f);
        loss = (c > 0.0f) ? (s / denom) : 0.0f;
    }
    #pragma unroll
    for (int off = 32; off > 0; off >>= 1)
        loss += __shfl_down(loss, off, 64);
    if (tid == 0) out[0] = loss * (1.0f / (float)B_IMG);
}

extern "C" void kernel_launch(void* const* d_in, const int* in_sizes, int n_in,
                              void* d_out, int out_size, void* d_ws, size_t ws_size,
                              hipStream_t stream)
{
    const float* reg     = (const float*)d_in[0];  // (B, A, 2)
    const float* anchors = (const float*)d_in[1];  // (1, A, 2)
    const float* ann     = (const float*)d_in[2];  // (B, M, 3)
    float* out = (float*)d_out;

    float* ws_sum = (float*)d_ws;
    float* ws_cnt = ws_sum + B_IMG;

    // d_ws is re-poisoned to 0xAA before every call — zero our accumulators.
    hipMemsetAsync(d_ws, 0, 2 * B_IMG * sizeof(float), stream);

    dim3 grid(A_N / 256, B_IMG);
    rl_main<<<grid, dim3(256), 0, stream>>>(reg, anchors, ann, ws_sum, ws_cnt);
    rl_final<<<1, 64, 0, stream>>>(ws_sum, ws_cnt, out);
}

// Round 2
// 82.239 us; speedup vs baseline: 1.5470x; 1.5470x over previous
//
#include <hip/hip_runtime.h>

#define B_IMG 16
#define A_N   65536
#define M_N   64
#define BLK   256
#define APT   4                                   // anchors per thread
#define BLOCKS_PER_IMG (A_N / (BLK * APT))        // 64
#define NSLOT (B_IMG * BLOCKS_PER_IMG)            // 1024 partial slots

// Main kernel: per-(image, anchor) IoU argmax via cross-multiplication
// (no division in the inner loop) + smooth-L1, block partials to ws.
__global__ __launch_bounds__(256) void rl_main(
    const float* __restrict__ reg,       // (B, A, 2)
    const float2* __restrict__ anchors,  // (A) as float2
    const float* __restrict__ ann,       // (B, M, 3)
    float2* __restrict__ partials,       // [NSLOT] (or [B] pairs in atomic mode)
    int atomic_mode)
{
    __shared__ float4 sbox[M_N];         // (b0, b1, area, 0) — sentinel for invalid
    const int b   = blockIdx.y;
    const int bx  = blockIdx.x;
    const int tid = threadIdx.x;

    if (tid < M_N) {
        const float* p = ann + (b * M_N + tid) * 3;
        float b0 = p[0], b1 = p[1], v = p[2];
        if (v == -1.0f) { b0 = 3.0e5f; b1 = 3.0e5f; }  // iw clamps to 0 -> iou 0 (<0.5, harmless)
        sbox[tid] = make_float4(b0, b1, b1 - b0, 0.0f);
    }
    __syncthreads();

    const int abase = bx * (BLK * APT) + tid;
    float ax[APT], ay[APT], aw[APT];
    float biw[APT], bua[APT];
    int   bidx[APT];
    #pragma unroll
    for (int j = 0; j < APT; ++j) {
        float2 an = anchors[abase + j * BLK];
        ax[j] = an.x; ay[j] = an.y; aw[j] = an.y - an.x;
        biw[j] = -1.0f; bua[j] = 1.0f; bidx[j] = 0;   // first m always updates
    }

    #pragma unroll 4
    for (int m = 0; m < M_N; ++m) {
        const float4 g = sbox[m];        // broadcast ds_read_b128
        #pragma unroll
        for (int j = 0; j < APT; ++j) {
            float iw = fminf(ay[j], g.y) - fmaxf(ax[j], g.x);
            iw = fmaxf(iw, 0.0f);
            float ua = (aw[j] + g.z) - iw;           // ua >= aw >= 20, no clamp needed
            // iou_m > iou_best  <=>  iw*bua > biw*ua (both denominators > 0)
            bool upd = iw * bua[j] > biw[j] * ua;
            biw[j]  = upd ? iw : biw[j];
            bua[j]  = upd ? ua : bua[j];
            bidx[j] = upd ? m  : bidx[j];
        }
    }

    float lsum = 0.0f, lcnt = 0.0f;
    #pragma unroll
    for (int j = 0; j < APT; ++j) {
        // pos <=> iou >= 0.5 <=> iw >= 0.5*ua (0.5*ua exact)
        if (biw[j] >= 0.5f * bua[j]) {
            lcnt += 1.0f;
            float4 g   = sbox[bidx[j]];
            float gw   = g.y - g.x;
            float gctr = g.x + 0.5f * gw;
            gw = fmaxf(gw, 1.0f);
            float actr = ax[j] + 0.5f * aw[j];
            float tdx = (gctr - actr) / aw[j] / 0.1f;
            float tdw = logf(gw / aw[j]) / 0.2f;
            const float2 r = ((const float2*)reg)[(size_t)b * A_N + abase + j * BLK];
            float d0 = fabsf(tdx - r.x);
            float d1 = fabsf(tdw - r.y);
            const float third = 1.0f / 9.0f;
            lsum += (d0 <= third) ? 4.5f * d0 * d0 : d0 - (0.5f / 9.0f);
            lsum += (d1 <= third) ? 4.5f * d1 * d1 : d1 - (0.5f / 9.0f);
        }
    }

    // wave reduction (64 lanes)
    #pragma unroll
    for (int off = 32; off > 0; off >>= 1) {
        lsum += __shfl_down(lsum, off, 64);
        lcnt += __shfl_down(lcnt, off, 64);
    }
    __shared__ float rs[4], rc[4];
    const int wave = tid >> 6, lane = tid & 63;
    if (lane == 0) { rs[wave] = lsum; rc[wave] = lcnt; }
    __syncthreads();
    if (tid == 0) {
        float s = rs[0] + rs[1] + rs[2] + rs[3];
        float c = rc[0] + rc[1] + rc[2] + rc[3];
        if (atomic_mode) {
            atomicAdd(&((float*)partials)[b * 2 + 0], s);
            atomicAdd(&((float*)partials)[b * 2 + 1], c);
        } else {
            partials[b * BLOCKS_PER_IMG + bx] = make_float2(s, c);
        }
    }
}

// Finalize (partials path): 16 waves, wave w reduces image w's 64 slots.
__global__ __launch_bounds__(1024) void rl_final_p(
    const float2* __restrict__ partials, float* __restrict__ out)
{
    __shared__ float simg[B_IMG];
    const int tid = threadIdx.x;
    const int w = tid >> 6, l = tid & 63;
    float2 p = partials[w * BLOCKS_PER_IMG + l];
    float s = p.x, c = p.y;
    #pragma unroll
    for (int off = 32; off > 0; off >>= 1) {
        s += __shfl_down(s, off, 64);
        c += __shfl_down(c, off, 64);
    }
    if (l == 0)
        simg[w] = (c > 0.0f) ? s / (2.0f * fmaxf(c, 1.0f)) : 0.0f;
    __syncthreads();
    if (tid == 0) {
        float t = 0.0f;
        #pragma unroll
        for (int i = 0; i < B_IMG; ++i) t += simg[i];
        out[0] = t * (1.0f / (float)B_IMG);
    }
}

// Finalize (atomic fallback): one wave.
__global__ void rl_final_a(const float* __restrict__ ws, float* __restrict__ out)
{
    const int tid = threadIdx.x;
    float loss = 0.0f;
    if (tid < B_IMG) {
        float s = ws[tid * 2 + 0], c = ws[tid * 2 + 1];
        loss = (c > 0.0f) ? s / (2.0f * fmaxf(c, 1.0f)) : 0.0f;
    }
    #pragma unroll
    for (int off = 32; off > 0; off >>= 1)
        loss += __shfl_down(loss, off, 64);
    if (tid == 0) out[0] = loss * (1.0f / (float)B_IMG);
}

extern "C" void kernel_launch(void* const* d_in, const int* in_sizes, int n_in,
                              void* d_out, int out_size, void* d_ws, size_t ws_size,
                              hipStream_t stream)
{
    const float*  reg     = (const float*)d_in[0];   // (B, A, 2)
    const float2* anchors = (const float2*)d_in[1];  // (1, A, 2)
    const float*  ann     = (const float*)d_in[2];   // (B, M, 3)
    float* out = (float*)d_out;

    const size_t need = NSLOT * sizeof(float2);
    dim3 grid(BLOCKS_PER_IMG, B_IMG);

    if (ws_size >= need) {
        float2* partials = (float2*)d_ws;   // every slot written -> no memset needed
        rl_main<<<grid, dim3(BLK), 0, stream>>>(reg, anchors, ann, partials, 0);
        rl_final_p<<<1, dim3(B_IMG * 64), 0, stream>>>(partials, out);
    } else {
        // atomic fallback: zero 16 (sum,cnt) pairs first
        hipMemsetAsync(d_ws, 0, 2 * B_IMG * sizeof(float), stream);
        rl_main<<<grid, dim3(BLK), 0, stream>>>(reg, anchors, ann, (float2*)d_ws, 1);
        rl_final_a<<<1, 64, 0, stream>>>((const float*)d_ws, out);
    }
}

// Round 3
// 69.329 us; speedup vs baseline: 1.8351x; 1.1862x over previous
//
#include <hip/hip_runtime.h>

#define B_IMG 16
#define A_N   65536
#define M_N   64
#define BLK   256
#define APT   4                                   // anchors per thread
#define BLOCKS_PER_IMG (A_N / (BLK * APT))        // 64
#define NSLOT (B_IMG * BLOCKS_PER_IMG)            // 1024 partial slots
#define NBINS 160                                 // 64-unit bins over [0, 10240)
#define INV_BINW (1.0f / 64.0f)
#define MARGIN 30.5f                              // gw/2 < 30 (+0.5 rounding slack)

// Main kernel: bin the 64 boxes by center (CSR in LDS), each anchor scans only
// candidate boxes whose center lies within +-MARGIN of its span. Exact:
// skipped boxes have iw=0 -> iou=0, which can neither be pos nor beat a
// positive candidate; argmax index only matters when iou_max >= 0.5.
__global__ __launch_bounds__(256) void rl_main(
    const float* __restrict__ reg,       // (B, A, 2)
    const float2* __restrict__ anchors,  // (A) as float2
    const float* __restrict__ ann,       // (B, M, 3)
    float2* __restrict__ partials,       // [NSLOT] (or [B] pairs in atomic mode)
    int atomic_mode)
{
    __shared__ float4 sboxes[M_N];       // sorted by (bin, m): (b0, b1, area, 0)
    __shared__ int    soff[NBINS + 1];   // CSR offsets
    __shared__ int    sbin[M_N];
    const int b   = blockIdx.y;
    const int bx  = blockIdx.x;
    const int tid = threadIdx.x;

    // Phase A: bin assignment (invalid -> sentinel bin NBINS, never scanned)
    float b0 = 0.f, b1 = 0.f;
    if (tid < M_N) {
        const float* p = ann + (b * M_N + tid) * 3;
        b0 = p[0]; b1 = p[1];
        float v = p[2];
        float gctr = b0 + 0.5f * (b1 - b0);
        int bin = (int)floorf(gctr * INV_BINW);
        bin = min(max(bin, 0), NBINS - 1);
        sbin[tid] = (v != -1.0f) ? bin : NBINS;
    }
    __syncthreads();

    // Phase B (tid<64): stable rank-sort by (bin, m); scatter box data.
    if (tid < M_N) {
        const int mybin = sbin[tid];
        int rank = 0;
        #pragma unroll 8
        for (int m = 0; m < M_N; ++m) {
            int bm = sbin[m];                     // uniform index -> LDS broadcast
            rank += (bm < mybin) || (bm == mybin && m < tid);
        }
        sboxes[rank] = make_float4(b0, b1, b1 - b0, 0.0f);
    }
    // Phase C (tid<=NBINS): CSR offsets by direct counting.
    if (tid <= NBINS) {
        int cnt = 0;
        #pragma unroll 8
        for (int m = 0; m < M_N; ++m)
            cnt += (sbin[m] < tid);
        soff[tid] = cnt;
    }
    __syncthreads();

    const int abase = bx * (BLK * APT) + tid;
    float lsum = 0.0f, lcnt = 0.0f;

    #pragma unroll
    for (int j = 0; j < APT; ++j) {
        const float2 an = anchors[abase + j * BLK];
        const float ax = an.x, ay = an.y, aw = ay - ax;
        int lo = (int)floorf((ax - MARGIN) * INV_BINW);
        int hi = (int)floorf((ay + MARGIN) * INV_BINW);
        lo = max(lo, 0);
        hi = min(hi, NBINS - 1);
        int k    = soff[lo];
        const int kend = soff[hi + 1];

        float biw = 0.0f, bua = 1.0f;
        int   bidx = 0;
        for (; k < kend; ++k) {
            const float4 g = sboxes[k];
            float iw = fminf(ay, g.y) - fmaxf(ax, g.x);
            iw = fmaxf(iw, 0.0f);
            float ua = (aw + g.z) - iw;           // ua >= aw >= 20 > 0
            // iou_k > iou_best  <=>  iw*bua > biw*ua
            if (iw * bua > biw * ua) { biw = iw; bua = ua; bidx = k; }
        }

        // pos <=> iou >= 0.5 <=> iw >= 0.5*ua ; biw==0 (no overlap) -> false
        if (biw >= 0.5f * bua) {
            lcnt += 1.0f;
            const float4 g = sboxes[bidx];
            float gw   = g.y - g.x;
            float gctr = g.x + 0.5f * gw;
            gw = fmaxf(gw, 1.0f);
            float actr = ax + 0.5f * aw;
            float tdx = (gctr - actr) / aw / 0.1f;
            float tdw = logf(gw / aw) / 0.2f;
            const float2 r = ((const float2*)reg)[(size_t)b * A_N + abase + j * BLK];
            float d0 = fabsf(tdx - r.x);
            float d1 = fabsf(tdw - r.y);
            const float third = 1.0f / 9.0f;
            lsum += (d0 <= third) ? 4.5f * d0 * d0 : d0 - (0.5f / 9.0f);
            lsum += (d1 <= third) ? 4.5f * d1 * d1 : d1 - (0.5f / 9.0f);
        }
    }

    // wave reduction (64 lanes)
    #pragma unroll
    for (int off = 32; off > 0; off >>= 1) {
        lsum += __shfl_down(lsum, off, 64);
        lcnt += __shfl_down(lcnt, off, 64);
    }
    __shared__ float rs[4], rc[4];
    const int wave = tid >> 6, lane = tid & 63;
    if (lane == 0) { rs[wave] = lsum; rc[wave] = lcnt; }
    __syncthreads();
    if (tid == 0) {
        float s = rs[0] + rs[1] + rs[2] + rs[3];
        float c = rc[0] + rc[1] + rc[2] + rc[3];
        if (atomic_mode) {
            atomicAdd(&((float*)partials)[b * 2 + 0], s);
            atomicAdd(&((float*)partials)[b * 2 + 1], c);
        } else {
            partials[b * BLOCKS_PER_IMG + bx] = make_float2(s, c);
        }
    }
}

// Finalize (partials path): 16 waves, wave w reduces image w's 64 slots.
__global__ __launch_bounds__(1024) void rl_final_p(
    const float2* __restrict__ partials, float* __restrict__ out)
{
    __shared__ float simg[B_IMG];
    const int tid = threadIdx.x;
    const int w = tid >> 6, l = tid & 63;
    float2 p = partials[w * BLOCKS_PER_IMG + l];
    float s = p.x, c = p.y;
    #pragma unroll
    for (int off = 32; off > 0; off >>= 1) {
        s += __shfl_down(s, off, 64);
        c += __shfl_down(c, off, 64);
    }
    if (l == 0)
        simg[w] = (c > 0.0f) ? s / (2.0f * fmaxf(c, 1.0f)) : 0.0f;
    __syncthreads();
    if (tid == 0) {
        float t = 0.0f;
        #pragma unroll
        for (int i = 0; i < B_IMG; ++i) t += simg[i];
        out[0] = t * (1.0f / (float)B_IMG);
    }
}

// Finalize (atomic fallback): one wave.
__global__ void rl_final_a(const float* __restrict__ ws, float* __restrict__ out)
{
    const int tid = threadIdx.x;
    float loss = 0.0f;
    if (tid < B_IMG) {
        float s = ws[tid * 2 + 0], c = ws[tid * 2 + 1];
        loss = (c > 0.0f) ? s / (2.0f * fmaxf(c, 1.0f)) : 0.0f;
    }
    #pragma unroll
    for (int off = 32; off > 0; off >>= 1)
        loss += __shfl_down(loss, off, 64);
    if (tid == 0) out[0] = loss * (1.0f / (float)B_IMG);
}

extern "C" void kernel_launch(void* const* d_in, const int* in_sizes, int n_in,
                              void* d_out, int out_size, void* d_ws, size_t ws_size,
                              hipStream_t stream)
{
    const float*  reg     = (const float*)d_in[0];   // (B, A, 2)
    const float2* anchors = (const float2*)d_in[1];  // (1, A, 2)
    const float*  ann     = (const float*)d_in[2];   // (B, M, 3)
    float* out = (float*)d_out;

    const size_t need = NSLOT * sizeof(float2);
    dim3 grid(BLOCKS_PER_IMG, B_IMG);

    if (ws_size >= need) {
        float2* partials = (float2*)d_ws;   // every slot written -> no memset needed
        rl_main<<<grid, dim3(BLK), 0, stream>>>(reg, anchors, ann, partials, 0);
        rl_final_p<<<1, dim3(B_IMG * 64), 0, stream>>>(partials, out);
    } else {
        hipMemsetAsync(d_ws, 0, 2 * B_IMG * sizeof(float), stream);
        rl_main<<<grid, dim3(BLK), 0, stream>>>(reg, anchors, ann, (float2*)d_ws, 1);
        rl_final_a<<<1, 64, 0, stream>>>((const float*)d_ws, out);
    }
}